// Round 1
// baseline (634.436 us; speedup 1.0000x reference)
//
#include <hip/hip_runtime.h>
#include <math.h>

#define NN 50000
#define NE 800000
#define INC 32
#define HIDC 64
#define OUTC 8

__device__ __forceinline__ float gelu_exact(float x){
    return 0.5f * x * (1.0f + erff(x * 0.70710678118654752f));
}

__global__ void k_zero_deg(int* deg){
    int i = blockIdx.x*blockDim.x + threadIdx.x;
    for (; i < NN; i += gridDim.x*blockDim.x) deg[i] = 0;
}

__global__ void k_hist(const int* __restrict__ dst, int* deg){
    int i = blockIdx.x*blockDim.x + threadIdx.x;
    for (; i < NE; i += gridDim.x*blockDim.x) atomicAdd(&deg[dst[i]], 1);
}

// single-block exclusive scan of deg -> row_ptr (+ fill_pos copy, inv_deg)
__global__ void k_scan(const int* __restrict__ deg, int* row_ptr, int* fill_pos,
                       float* inv_deg){
    __shared__ int sd[1024];
    int tid = threadIdx.x;
    int carry = 0;
    for (int base = 0; base < NN; base += 1024){
        int v = (base+tid < NN) ? deg[base+tid] : 0;
        sd[tid] = v;
        __syncthreads();
        for (int off = 1; off < 1024; off <<= 1){
            int t = (tid >= off) ? sd[tid-off] : 0;
            __syncthreads();
            sd[tid] += t;
            __syncthreads();
        }
        int excl = sd[tid] - v + carry;
        if (base+tid < NN){
            row_ptr[base+tid]  = excl;
            fill_pos[base+tid] = excl;
            inv_deg[base+tid]  = 1.0f / (float)max(v, 1);
        }
        carry += sd[1023];
        __syncthreads();
    }
    if (tid == 0) row_ptr[NN] = NE;
}

__global__ void k_fill(const int* __restrict__ src, const int* __restrict__ dst,
                       int* fill_pos, int* col){
    int i = blockIdx.x*blockDim.x + threadIdx.x;
    for (; i < NE; i += gridDim.x*blockDim.x){
        int d = dst[i];
        int p = atomicAdd(&fill_pos[d], 1);
        col[p] = src[i];
    }
}

// encoder: h = gelu(x@w1+b1)@w2+b2 ; one wave per node, lane = out feature
__global__ __launch_bounds__(256) void k_encoder(
    const float* __restrict__ x,
    const float* __restrict__ w1, const float* __restrict__ b1,
    const float* __restrict__ w2, const float* __restrict__ b2,
    float* __restrict__ h)
{
    __shared__ float w1s[INC*HIDC];
    __shared__ float w2s[HIDC*HIDC];
    __shared__ float b1s[HIDC], b2s[HIDC];
    __shared__ float xs[4][INC];
    __shared__ float ts[4][HIDC];
    int tid = threadIdx.x;
    for (int i = tid; i < INC*HIDC;  i += 256) w1s[i] = w1[i];
    for (int i = tid; i < HIDC*HIDC; i += 256) w2s[i] = w2[i];
    if (tid < HIDC){ b1s[tid] = b1[tid]; b2s[tid] = b2[tid]; }
    __syncthreads();
    int w = tid >> 6, f = tid & 63;
    for (int base = blockIdx.x*4; base < NN; base += gridDim.x*4){
        int node = base + w;
        bool valid = node < NN;
        if (valid && f < INC) xs[w][f] = x[node*INC + f];
        __syncthreads();
        if (valid){
            float t = b1s[f];
            #pragma unroll
            for (int k = 0; k < INC; k++) t += xs[w][k]*w1s[k*HIDC+f];
            ts[w][f] = gelu_exact(t);
        }
        __syncthreads();
        if (valid){
            float o = b2s[f];
            #pragma unroll 16
            for (int k = 0; k < HIDC; k++) o += ts[w][k]*w2s[k*HIDC+f];
            h[node*HIDC+f] = o;
        }
        __syncthreads();
    }
}

// fused SAGE layer: h_out = gelu( (mean_agg(h_in) @ wl) + (h_in @ wr) + b )
__global__ __launch_bounds__(256) void k_sage(
    const float* __restrict__ h_in,
    const float* __restrict__ wl, const float* __restrict__ wr,
    const float* __restrict__ b,
    const int* __restrict__ row_ptr, const int* __restrict__ col,
    const float* __restrict__ inv_deg,
    float* __restrict__ h_out)
{
    __shared__ float wls[HIDC*HIDC], wrs[HIDC*HIDC];
    __shared__ float bs[HIDC];
    __shared__ float hs[4][HIDC], as[4][HIDC];
    int tid = threadIdx.x;
    for (int i = tid; i < HIDC*HIDC; i += 256){ wls[i] = wl[i]; wrs[i] = wr[i]; }
    if (tid < HIDC) bs[tid] = b[tid];
    __syncthreads();
    int w = tid >> 6, f = tid & 63;
    for (int base = blockIdx.x*4; base < NN; base += gridDim.x*4){
        int node = base + w;
        bool valid = node < NN;          // wave-uniform
        if (valid){
            float hval = h_in[node*HIDC+f];
            float acc = 0.f;
            int s0 = row_ptr[node], s1 = row_ptr[node+1];
            for (int p0 = s0; p0 < s1; p0 += 64){
                int cnt = s1 - p0; if (cnt > 64) cnt = 64;
                int cidx = (f < cnt) ? col[p0+f] : 0;
                for (int j = 0; j < cnt; j++){
                    int s = __shfl(cidx, j);
                    acc += h_in[s*HIDC+f];
                }
            }
            acc *= inv_deg[node];
            hs[w][f] = hval;
            as[w][f] = acc;
        }
        __syncthreads();
        if (valid){
            float o = bs[f];
            #pragma unroll 16
            for (int k = 0; k < HIDC; k++)
                o += as[w][k]*wls[k*HIDC+f] + hs[w][k]*wrs[k*HIDC+f];
            h_out[node*HIDC+f] = gelu_exact(o);
        }
        __syncthreads();
    }
}

// decoder: out = gelu(h@w1+b1)@w2+b2
__global__ __launch_bounds__(256) void k_decoder(
    const float* __restrict__ h,
    const float* __restrict__ w1, const float* __restrict__ b1,
    const float* __restrict__ w2, const float* __restrict__ b2,
    float* __restrict__ out)
{
    __shared__ float w1s[HIDC*HIDC];
    __shared__ float w2s[HIDC*OUTC];
    __shared__ float b1s[HIDC], b2s[OUTC];
    __shared__ float hs[4][HIDC], ts[4][HIDC];
    int tid = threadIdx.x;
    for (int i = tid; i < HIDC*HIDC; i += 256) w1s[i] = w1[i];
    for (int i = tid; i < HIDC*OUTC; i += 256) w2s[i] = w2[i];
    if (tid < HIDC) b1s[tid] = b1[tid];
    if (tid < OUTC) b2s[tid] = b2[tid];
    __syncthreads();
    int w = tid >> 6, f = tid & 63;
    for (int base = blockIdx.x*4; base < NN; base += gridDim.x*4){
        int node = base + w;
        bool valid = node < NN;
        if (valid) hs[w][f] = h[node*HIDC+f];
        __syncthreads();
        if (valid){
            float t = b1s[f];
            #pragma unroll 16
            for (int k = 0; k < HIDC; k++) t += hs[w][k]*w1s[k*HIDC+f];
            ts[w][f] = gelu_exact(t);
        }
        __syncthreads();
        if (valid && f < OUTC){
            float o = b2s[f];
            #pragma unroll 16
            for (int k = 0; k < HIDC; k++) o += ts[w][k]*w2s[k*OUTC+f];
            out[node*OUTC+f] = o;
        }
        __syncthreads();
    }
}

extern "C" void kernel_launch(void* const* d_in, const int* in_sizes, int n_in,
                              void* d_out, int out_size, void* d_ws, size_t ws_size,
                              hipStream_t stream){
    const float* x      = (const float*)d_in[0];
    const int*   ei     = (const int*)  d_in[1];
    const float* enc_w1 = (const float*)d_in[2];
    const float* enc_b1 = (const float*)d_in[3];
    const float* enc_w2 = (const float*)d_in[4];
    const float* enc_b2 = (const float*)d_in[5];
    const float* sage_wl= (const float*)d_in[6];
    const float* sage_wr= (const float*)d_in[7];
    const float* sage_b = (const float*)d_in[8];
    const float* dec_w1 = (const float*)d_in[9];
    const float* dec_b1 = (const float*)d_in[10];
    const float* dec_w2 = (const float*)d_in[11];
    const float* dec_b2 = (const float*)d_in[12];
    float* out = (float*)d_out;

    char* ws = (char*)d_ws;
    size_t off = 0;
    auto alloc = [&](size_t bytes)->void*{
        void* p = ws + off; off = (off + bytes + 255) & ~(size_t)255; return p;
    };
    int*   deg      = (int*)  alloc((size_t)NN*4);
    int*   row_ptr  = (int*)  alloc((size_t)(NN+1)*4);
    int*   fill_pos = (int*)  alloc((size_t)NN*4);
    int*   col      = (int*)  alloc((size_t)NE*4);
    float* inv_deg  = (float*)alloc((size_t)NN*4);
    float* h0       = (float*)alloc((size_t)NN*HIDC*4);
    float* h1       = (float*)alloc((size_t)NN*HIDC*4);

    const int* srcv = ei;        // edge_index row 0
    const int* dstv = ei + NE;   // edge_index row 1

    hipLaunchKernelGGL(k_zero_deg, dim3(256),  dim3(256),  0, stream, deg);
    hipLaunchKernelGGL(k_hist,     dim3(1024), dim3(256),  0, stream, dstv, deg);
    hipLaunchKernelGGL(k_scan,     dim3(1),    dim3(1024), 0, stream, deg, row_ptr, fill_pos, inv_deg);
    hipLaunchKernelGGL(k_fill,     dim3(1024), dim3(256),  0, stream, srcv, dstv, fill_pos, col);

    hipLaunchKernelGGL(k_encoder,  dim3(1024), dim3(256),  0, stream,
                       x, enc_w1, enc_b1, enc_w2, enc_b2, h0);

    const float* hin = h0; float* hout = h1;
    for (int l = 0; l < 3; l++){
        hipLaunchKernelGGL(k_sage, dim3(1024), dim3(256), 0, stream,
                           hin, sage_wl + (size_t)l*HIDC*HIDC,
                           sage_wr + (size_t)l*HIDC*HIDC,
                           sage_b  + (size_t)l*HIDC,
                           row_ptr, col, inv_deg, hout);
        float* t = (float*)hin; hin = hout; hout = t;
    }

    hipLaunchKernelGGL(k_decoder,  dim3(1024), dim3(256),  0, stream,
                       hin, dec_w1, dec_b1, dec_w2, dec_b2, out);
}

// Round 2
// 398.835 us; speedup vs baseline: 1.5907x; 1.5907x over previous
//
#include <hip/hip_runtime.h>
#include <math.h>

#define NN 50000
#define NE 800000
#define INC 32
#define HIDC 64
#define OUTC 8
#define NB_SCAN ((NN + 1023) / 1024)

__device__ __forceinline__ float gelu_exact(float x){
    return 0.5f * x * (1.0f + erff(x * 0.70710678118654752f));
}
// broadcast lane `lane`'s value of v to all lanes (compile-time lane -> v_readlane imm)
__device__ __forceinline__ float bcastf(float v, int lane){
    return __uint_as_float(__builtin_amdgcn_readlane(__float_as_uint(v), lane));
}

__global__ void k_zero_deg(int* deg){
    int i = blockIdx.x*blockDim.x + threadIdx.x;
    for (; i < NN; i += gridDim.x*blockDim.x) deg[i] = 0;
}

__global__ void k_hist(const int* __restrict__ dst, int* deg){
    int i = blockIdx.x*blockDim.x + threadIdx.x;
    for (; i < NE; i += gridDim.x*blockDim.x) atomicAdd(&deg[dst[i]], 1);
}

// hierarchical scan: per-chunk local exclusive scan + chunk totals
__global__ __launch_bounds__(1024) void k_scan1(const int* __restrict__ deg,
                                                int* loc, int* bsum){
    __shared__ int sd[1024];
    int b = blockIdx.x, tid = threadIdx.x, g = b*1024 + tid;
    int v = (g < NN) ? deg[g] : 0;
    sd[tid] = v;
    __syncthreads();
    for (int off = 1; off < 1024; off <<= 1){
        int t = (tid >= off) ? sd[tid-off] : 0;
        __syncthreads();
        sd[tid] += t;
        __syncthreads();
    }
    if (g < NN) loc[g] = sd[tid] - v;
    if (tid == 1023) bsum[b] = sd[1023];
}

// exclusive scan of NB_SCAN (<=64) chunk sums, single wave
__global__ void k_scan2(int* bsum){
    int tid = threadIdx.x;
    int orig = (tid < NB_SCAN) ? bsum[tid] : 0;
    int v = orig;
    for (int off = 1; off < 64; off <<= 1){
        int t = __shfl_up(v, off);
        if (tid >= off) v += t;
    }
    if (tid < NB_SCAN) bsum[tid] = v - orig;
}

__global__ void k_scan3(const int* __restrict__ deg, const int* __restrict__ loc,
                        const int* __restrict__ bsum,
                        int* row_ptr, int* fill_pos, float* inv_deg){
    int g = blockIdx.x*blockDim.x + threadIdx.x;
    if (g < NN){
        int e = loc[g] + bsum[g >> 10];
        row_ptr[g] = e; fill_pos[g] = e;
        inv_deg[g] = 1.0f / (float)max(deg[g], 1);
    }
    if (g == 0) row_ptr[NN] = NE;
}

__global__ void k_fill(const int* __restrict__ src, const int* __restrict__ dst,
                       int* fill_pos, int* col){
    int i = blockIdx.x*blockDim.x + threadIdx.x;
    for (; i < NE; i += gridDim.x*blockDim.x){
        int d = dst[i];
        int p = atomicAdd(&fill_pos[d], 1);
        col[p] = src[i];
    }
}

// encoder: h = gelu(x@w1+b1)@w2+b2 ; one wave per node, lane = feature
// broadcasts via readlane -> no per-node barriers, waves independent
__global__ __launch_bounds__(512) void k_encoder(
    const float* __restrict__ x,
    const float* __restrict__ w1, const float* __restrict__ b1,
    const float* __restrict__ w2, const float* __restrict__ b2,
    float* __restrict__ h)
{
    __shared__ float w1s[INC*HIDC];
    __shared__ float w2s[HIDC*HIDC];
    int tid = threadIdx.x;
    for (int i = tid; i < INC*HIDC;  i += 512) w1s[i] = w1[i];
    for (int i = tid; i < HIDC*HIDC; i += 512) w2s[i] = w2[i];
    __syncthreads();
    int w = tid >> 6, f = tid & 63;
    float b1f = b1[f], b2f = b2[f];
    for (int node = blockIdx.x*8 + w; node < NN; node += gridDim.x*8){
        float xv = (f < INC) ? x[node*INC + f] : 0.f;
        float t = b1f;
        #pragma unroll
        for (int k = 0; k < INC; k++) t += bcastf(xv, k) * w1s[k*HIDC + f];
        t = gelu_exact(t);
        float o = b2f;
        #pragma unroll
        for (int k = 0; k < HIDC; k++) o += bcastf(t, k) * w2s[k*HIDC + f];
        h[node*HIDC + f] = o;
    }
}

// fused SAGE layer: h_out = gelu( mean_agg(h_in) @ wl + h_in @ wr + b )
__global__ __launch_bounds__(512) void k_sage(
    const float* __restrict__ h_in,
    const float* __restrict__ wl, const float* __restrict__ wr,
    const float* __restrict__ b,
    const int* __restrict__ row_ptr, const int* __restrict__ col,
    const float* __restrict__ inv_deg,
    float* __restrict__ h_out)
{
    __shared__ float wls[HIDC*HIDC], wrs[HIDC*HIDC];
    int tid = threadIdx.x;
    for (int i = tid; i < HIDC*HIDC; i += 512){ wls[i] = wl[i]; wrs[i] = wr[i]; }
    __syncthreads();
    int w = tid >> 6, f = tid & 63;
    float bf = b[f];
    for (int node = blockIdx.x*8 + w; node < NN; node += gridDim.x*8){
        float hval = h_in[node*HIDC + f];
        int s0 = row_ptr[node], s1 = row_ptr[node+1];
        float a0=0.f,a1=0.f,a2=0.f,a3=0.f,a4=0.f,a5=0.f,a6=0.f,a7=0.f;
        for (int p0 = s0; p0 < s1; p0 += 64){
            int cnt = s1 - p0; if (cnt > 64) cnt = 64;
            int cidx = (f < cnt) ? col[p0 + f] : 0;
            for (int j = 0; j < cnt; j += 8){
                // lanes >= cnt hold cidx=0 -> safe dummy index
                int i0=__shfl(cidx,j+0), i1=__shfl(cidx,j+1);
                int i2=__shfl(cidx,j+2), i3=__shfl(cidx,j+3);
                int i4=__shfl(cidx,j+4), i5=__shfl(cidx,j+5);
                int i6=__shfl(cidx,j+6), i7=__shfl(cidx,j+7);
                float v0=h_in[i0*HIDC+f], v1=h_in[i1*HIDC+f];
                float v2=h_in[i2*HIDC+f], v3=h_in[i3*HIDC+f];
                float v4=h_in[i4*HIDC+f], v5=h_in[i5*HIDC+f];
                float v6=h_in[i6*HIDC+f], v7=h_in[i7*HIDC+f];
                a0 += v0;                       // j+0 < cnt always
                a1 += (j+1 < cnt) ? v1 : 0.f;
                a2 += (j+2 < cnt) ? v2 : 0.f;
                a3 += (j+3 < cnt) ? v3 : 0.f;
                a4 += (j+4 < cnt) ? v4 : 0.f;
                a5 += (j+5 < cnt) ? v5 : 0.f;
                a6 += (j+6 < cnt) ? v6 : 0.f;
                a7 += (j+7 < cnt) ? v7 : 0.f;
            }
        }
        float acc = ((a0+a1)+(a2+a3)) + ((a4+a5)+(a6+a7));
        acc *= inv_deg[node];
        float o = bf;
        #pragma unroll
        for (int k = 0; k < HIDC; k++)
            o += bcastf(acc, k)*wls[k*HIDC + f] + bcastf(hval, k)*wrs[k*HIDC + f];
        h_out[node*HIDC + f] = gelu_exact(o);
    }
}

// decoder: out = gelu(h@w1+b1)@w2+b2
__global__ __launch_bounds__(512) void k_decoder(
    const float* __restrict__ h,
    const float* __restrict__ w1, const float* __restrict__ b1,
    const float* __restrict__ w2, const float* __restrict__ b2,
    float* __restrict__ out)
{
    __shared__ float w1s[HIDC*HIDC];
    __shared__ float w2s[HIDC*OUTC];
    int tid = threadIdx.x;
    for (int i = tid; i < HIDC*HIDC; i += 512) w1s[i] = w1[i];
    for (int i = tid; i < HIDC*OUTC; i += 512) w2s[i] = w2[i];
    __syncthreads();
    int w = tid >> 6, f = tid & 63;
    int fo = f & (OUTC-1);
    float b1f = b1[f];
    float b2f = b2[fo];
    for (int node = blockIdx.x*8 + w; node < NN; node += gridDim.x*8){
        float hv = h[node*HIDC + f];
        float t = b1f;
        #pragma unroll
        for (int k = 0; k < HIDC; k++) t += bcastf(hv, k) * w1s[k*HIDC + f];
        t = gelu_exact(t);
        float o = b2f;
        #pragma unroll
        for (int k = 0; k < HIDC; k++) o += bcastf(t, k) * w2s[k*OUTC + fo];
        if (f < OUTC) out[node*OUTC + f] = o;
    }
}

extern "C" void kernel_launch(void* const* d_in, const int* in_sizes, int n_in,
                              void* d_out, int out_size, void* d_ws, size_t ws_size,
                              hipStream_t stream){
    const float* x      = (const float*)d_in[0];
    const int*   ei     = (const int*)  d_in[1];
    const float* enc_w1 = (const float*)d_in[2];
    const float* enc_b1 = (const float*)d_in[3];
    const float* enc_w2 = (const float*)d_in[4];
    const float* enc_b2 = (const float*)d_in[5];
    const float* sage_wl= (const float*)d_in[6];
    const float* sage_wr= (const float*)d_in[7];
    const float* sage_b = (const float*)d_in[8];
    const float* dec_w1 = (const float*)d_in[9];
    const float* dec_b1 = (const float*)d_in[10];
    const float* dec_w2 = (const float*)d_in[11];
    const float* dec_b2 = (const float*)d_in[12];
    float* out = (float*)d_out;

    char* ws = (char*)d_ws;
    size_t off = 0;
    auto alloc = [&](size_t bytes)->void*{
        void* p = ws + off; off = (off + bytes + 255) & ~(size_t)255; return p;
    };
    int*   deg      = (int*)  alloc((size_t)NN*4);
    int*   loc      = (int*)  alloc((size_t)NN*4);
    int*   bsum     = (int*)  alloc(64*4);
    int*   row_ptr  = (int*)  alloc((size_t)(NN+1)*4);
    int*   fill_pos = (int*)  alloc((size_t)NN*4);
    int*   col      = (int*)  alloc((size_t)NE*4);
    float* inv_deg  = (float*)alloc((size_t)NN*4);
    float* h0       = (float*)alloc((size_t)NN*HIDC*4);
    float* h1       = (float*)alloc((size_t)NN*HIDC*4);

    const int* srcv = ei;        // edge_index row 0
    const int* dstv = ei + NE;   // edge_index row 1

    hipLaunchKernelGGL(k_zero_deg, dim3(256),     dim3(256),  0, stream, deg);
    hipLaunchKernelGGL(k_hist,     dim3(1024),    dim3(256),  0, stream, dstv, deg);
    hipLaunchKernelGGL(k_scan1,    dim3(NB_SCAN), dim3(1024), 0, stream, deg, loc, bsum);
    hipLaunchKernelGGL(k_scan2,    dim3(1),       dim3(64),   0, stream, bsum);
    hipLaunchKernelGGL(k_scan3,    dim3((NN+255)/256), dim3(256), 0, stream,
                       deg, loc, bsum, row_ptr, fill_pos, inv_deg);
    hipLaunchKernelGGL(k_fill,     dim3(1024),    dim3(256),  0, stream, srcv, dstv, fill_pos, col);

    hipLaunchKernelGGL(k_encoder,  dim3(1024),    dim3(512),  0, stream,
                       x, enc_w1, enc_b1, enc_w2, enc_b2, h0);

    const float* hin = h0; float* hout = h1;
    for (int l = 0; l < 3; l++){
        hipLaunchKernelGGL(k_sage, dim3(1024), dim3(512), 0, stream,
                           hin, sage_wl + (size_t)l*HIDC*HIDC,
                           sage_wr + (size_t)l*HIDC*HIDC,
                           sage_b  + (size_t)l*HIDC,
                           row_ptr, col, inv_deg, hout);
        float* t = (float*)hin; hin = hout; hout = t;
    }

    hipLaunchKernelGGL(k_decoder,  dim3(1024),    dim3(512),  0, stream,
                       hin, dec_w1, dec_b1, dec_w2, dec_b2, out);
}

// Round 3
// 384.520 us; speedup vs baseline: 1.6499x; 1.0372x over previous
//
#include <hip/hip_runtime.h>
#include <math.h>

#define NN 50000
#define NE 800000
#define INC 32
#define HIDC 64
#define OUTC 8
#define NB_SCAN ((NN + 1023) / 1024)

__device__ __forceinline__ float gelu_exact(float x){
    return 0.5f * x * (1.0f + erff(x * 0.70710678118654752f));
}
// broadcast lane's value (compile-time lane -> v_readlane imm)
__device__ __forceinline__ float bcastf(float v, int lane){
    return __uint_as_float(__builtin_amdgcn_readlane(__float_as_uint(v), lane));
}

__global__ void k_zero_deg(int* deg){
    int i = blockIdx.x*blockDim.x + threadIdx.x;
    for (; i < NN; i += gridDim.x*blockDim.x) deg[i] = 0;
}

// zero the dummy row NN of both h buffers (gather targets for padded edges)
__global__ void k_zero_rows(float* h0, float* h1){
    int i = threadIdx.x;
    if (i < HIDC) h0[(size_t)NN*HIDC + i] = 0.f;
    else          h1[(size_t)NN*HIDC + (i-HIDC)] = 0.f;
}

__global__ void k_hist(const int* __restrict__ dst, int* deg){
    int i = blockIdx.x*blockDim.x + threadIdx.x;
    for (; i < NE; i += gridDim.x*blockDim.x) atomicAdd(&deg[dst[i]], 1);
}

// hierarchical scan: per-chunk local exclusive scan + chunk totals
__global__ __launch_bounds__(1024) void k_scan1(const int* __restrict__ deg,
                                                int* loc, int* bsum){
    __shared__ int sd[1024];
    int b = blockIdx.x, tid = threadIdx.x, g = b*1024 + tid;
    int v = (g < NN) ? deg[g] : 0;
    sd[tid] = v;
    __syncthreads();
    for (int off = 1; off < 1024; off <<= 1){
        int t = (tid >= off) ? sd[tid-off] : 0;
        __syncthreads();
        sd[tid] += t;
        __syncthreads();
    }
    if (g < NN) loc[g] = sd[tid] - v;
    if (tid == 1023) bsum[b] = sd[1023];
}

__global__ void k_scan2(int* bsum){
    int tid = threadIdx.x;
    int orig = (tid < NB_SCAN) ? bsum[tid] : 0;
    int v = orig;
    for (int off = 1; off < 64; off <<= 1){
        int t = __shfl_up(v, off);
        if (tid >= off) v += t;
    }
    if (tid < NB_SCAN) bsum[tid] = v - orig;
}

__global__ void k_scan3(const int* __restrict__ deg, const int* __restrict__ loc,
                        const int* __restrict__ bsum,
                        int* row_ptr, int* fill_pos, float* inv_deg){
    int g = blockIdx.x*blockDim.x + threadIdx.x;
    if (g < NN){
        int e = loc[g] + bsum[g >> 10];
        row_ptr[g] = e; fill_pos[g] = e;
        inv_deg[g] = 1.0f / (float)max(deg[g], 1);
    }
    if (g == 0) row_ptr[NN] = NE;
}

__global__ void k_fill(const int* __restrict__ src, const int* __restrict__ dst,
                       int* fill_pos, int* col){
    int i = blockIdx.x*blockDim.x + threadIdx.x;
    for (; i < NE; i += gridDim.x*blockDim.x){
        int d = dst[i];
        int p = atomicAdd(&fill_pos[d], 1);
        col[p] = src[i];
    }
}

// encoder: h = gelu(x@w1+b1)@w2+b2 ; weights persisted in VGPRs, zero LDS
__global__ __launch_bounds__(256, 3) void k_encoder(
    const float* __restrict__ x,
    const float* __restrict__ w1, const float* __restrict__ b1,
    const float* __restrict__ w2, const float* __restrict__ b2,
    float* __restrict__ h)
{
    int tid = threadIdx.x;
    int w = tid >> 6, f = tid & 63;
    float w1r[INC], w2r[HIDC];
    #pragma unroll
    for (int k = 0; k < INC; k++)  w1r[k] = w1[k*HIDC + f];
    #pragma unroll
    for (int k = 0; k < HIDC; k++) w2r[k] = w2[k*HIDC + f];
    float b1f = b1[f], b2f = b2[f];
    int qoff = (f & 7) * 4;   // 8-lane groups each cover the 32-float x row
    for (int node = blockIdx.x*4 + w; node < NN; node += gridDim.x*4){
        float4 xv = *(const float4*)&x[(size_t)node*INC + qoff];
        float xa[4] = {xv.x, xv.y, xv.z, xv.w};
        float t = b1f;
        #pragma unroll
        for (int k = 0; k < INC; k++)
            t += bcastf(xa[k & 3], k >> 2) * w1r[k];
        t = gelu_exact(t);
        float o = b2f;
        #pragma unroll
        for (int k = 0; k < HIDC; k++)
            o += bcastf(t, k) * w2r[k];
        h[(size_t)node*HIDC + f] = o;
    }
}

// fused SAGE layer: h_out = gelu( mean_agg(h_in) @ wl + h_in @ wr + b )
// weights in VGPRs; float4 gather, 4 edges per wave-iteration; padded edges
// read the zero row at index NN (no predication).
__global__ __launch_bounds__(256, 3) void k_sage(
    const float* __restrict__ h_in,
    const float* __restrict__ wl, const float* __restrict__ wr,
    const float* __restrict__ b,
    const int* __restrict__ row_ptr, const int* __restrict__ col,
    const float* __restrict__ inv_deg,
    float* __restrict__ h_out)
{
    int tid = threadIdx.x;
    int w = tid >> 6, f = tid & 63;
    float wlr[HIDC], wrr[HIDC];
    #pragma unroll
    for (int k = 0; k < HIDC; k++){
        wlr[k] = wl[k*HIDC + f];
        wrr[k] = wr[k*HIDC + f];
    }
    float bf = b[f];
    int g    = f >> 4;        // edge group 0..3
    int qoff = (f & 15) * 4;  // feature quad base

    for (int node = blockIdx.x*4 + w; node < NN; node += gridDim.x*4){
        float4 hq = *(const float4*)&h_in[(size_t)node*HIDC + qoff];
        float hh[4] = {hq.x, hq.y, hq.z, hq.w};
        int s0 = row_ptr[node], s1 = row_ptr[node+1];
        float a0 = 0.f, a1 = 0.f, a2 = 0.f, a3 = 0.f;
        for (int p0 = s0; p0 < s1; p0 += 64){
            int cnt = s1 - p0; if (cnt > 64) cnt = 64;
            int cidx = (f < cnt) ? col[p0 + f] : NN;   // NN -> zero row
            int nq = (cnt + 3) >> 2;
            for (int t = 0; t < nq; t++){
                int sidx = __shfl(cidx, t*4 + g);
                float4 v = *(const float4*)&h_in[(size_t)sidx*HIDC + qoff];
                a0 += v.x; a1 += v.y; a2 += v.z; a3 += v.w;
            }
        }
        // reduce across the 4 edge groups (lanes 16 apart hold same features)
        a0 += __shfl_xor(a0, 16); a0 += __shfl_xor(a0, 32);
        a1 += __shfl_xor(a1, 16); a1 += __shfl_xor(a1, 32);
        a2 += __shfl_xor(a2, 16); a2 += __shfl_xor(a2, 32);
        a3 += __shfl_xor(a3, 16); a3 += __shfl_xor(a3, 32);
        float idg = inv_deg[node];
        float aa[4] = {a0*idg, a1*idg, a2*idg, a3*idg};
        float o = bf;
        #pragma unroll
        for (int k = 0; k < HIDC; k++){
            float ak = bcastf(aa[k & 3], k >> 2);
            float hk = bcastf(hh[k & 3], k >> 2);
            o += ak * wlr[k] + hk * wrr[k];
        }
        h_out[(size_t)node*HIDC + f] = gelu_exact(o);
    }
}

// decoder: out = gelu(h@w1+b1)@w2+b2 ; weights in VGPRs
__global__ __launch_bounds__(256, 3) void k_decoder(
    const float* __restrict__ h,
    const float* __restrict__ w1, const float* __restrict__ b1,
    const float* __restrict__ w2, const float* __restrict__ b2,
    float* __restrict__ out)
{
    int tid = threadIdx.x;
    int w = tid >> 6, f = tid & 63;
    int fo = f & (OUTC-1);
    float w1r[HIDC], w2r[HIDC];
    #pragma unroll
    for (int k = 0; k < HIDC; k++){
        w1r[k] = w1[k*HIDC + f];
        w2r[k] = w2[k*OUTC + fo];
    }
    float b1f = b1[f], b2f = b2[fo];
    for (int node = blockIdx.x*4 + w; node < NN; node += gridDim.x*4){
        float hv = h[(size_t)node*HIDC + f];
        float t = b1f;
        #pragma unroll
        for (int k = 0; k < HIDC; k++)
            t += bcastf(hv, k) * w1r[k];
        t = gelu_exact(t);
        float o = b2f;
        #pragma unroll
        for (int k = 0; k < HIDC; k++)
            o += bcastf(t, k) * w2r[k];
        if (f < OUTC) out[(size_t)node*OUTC + f] = o;
    }
}

extern "C" void kernel_launch(void* const* d_in, const int* in_sizes, int n_in,
                              void* d_out, int out_size, void* d_ws, size_t ws_size,
                              hipStream_t stream){
    const float* x      = (const float*)d_in[0];
    const int*   ei     = (const int*)  d_in[1];
    const float* enc_w1 = (const float*)d_in[2];
    const float* enc_b1 = (const float*)d_in[3];
    const float* enc_w2 = (const float*)d_in[4];
    const float* enc_b2 = (const float*)d_in[5];
    const float* sage_wl= (const float*)d_in[6];
    const float* sage_wr= (const float*)d_in[7];
    const float* sage_b = (const float*)d_in[8];
    const float* dec_w1 = (const float*)d_in[9];
    const float* dec_b1 = (const float*)d_in[10];
    const float* dec_w2 = (const float*)d_in[11];
    const float* dec_b2 = (const float*)d_in[12];
    float* out = (float*)d_out;

    char* ws = (char*)d_ws;
    size_t off = 0;
    auto alloc = [&](size_t bytes)->void*{
        void* p = ws + off; off = (off + bytes + 255) & ~(size_t)255; return p;
    };
    int*   deg      = (int*)  alloc((size_t)NN*4);
    int*   loc      = (int*)  alloc((size_t)NN*4);
    int*   bsum     = (int*)  alloc(64*4);
    int*   row_ptr  = (int*)  alloc((size_t)(NN+1)*4);
    int*   fill_pos = (int*)  alloc((size_t)NN*4);
    int*   col      = (int*)  alloc((size_t)NE*4);
    float* inv_deg  = (float*)alloc((size_t)NN*4);
    float* h0       = (float*)alloc((size_t)(NN+1)*HIDC*4);  // +1 zero row
    float* h1       = (float*)alloc((size_t)(NN+1)*HIDC*4);

    const int* srcv = ei;        // edge_index row 0
    const int* dstv = ei + NE;   // edge_index row 1

    hipLaunchKernelGGL(k_zero_deg, dim3(256),     dim3(256),  0, stream, deg);
    hipLaunchKernelGGL(k_zero_rows,dim3(1),       dim3(128),  0, stream, h0, h1);
    hipLaunchKernelGGL(k_hist,     dim3(1024),    dim3(256),  0, stream, dstv, deg);
    hipLaunchKernelGGL(k_scan1,    dim3(NB_SCAN), dim3(1024), 0, stream, deg, loc, bsum);
    hipLaunchKernelGGL(k_scan2,    dim3(1),       dim3(64),   0, stream, bsum);
    hipLaunchKernelGGL(k_scan3,    dim3((NN+255)/256), dim3(256), 0, stream,
                       deg, loc, bsum, row_ptr, fill_pos, inv_deg);
    hipLaunchKernelGGL(k_fill,     dim3(1024),    dim3(256),  0, stream, srcv, dstv, fill_pos, col);

    hipLaunchKernelGGL(k_encoder,  dim3(1024),    dim3(256),  0, stream,
                       x, enc_w1, enc_b1, enc_w2, enc_b2, h0);

    const float* hin = h0; float* hout = h1;
    for (int l = 0; l < 3; l++){
        hipLaunchKernelGGL(k_sage, dim3(768), dim3(256), 0, stream,
                           hin, sage_wl + (size_t)l*HIDC*HIDC,
                           sage_wr + (size_t)l*HIDC*HIDC,
                           sage_b  + (size_t)l*HIDC,
                           row_ptr, col, inv_deg, hout);
        float* t = (float*)hin; hin = hout; hout = t;
    }

    hipLaunchKernelGGL(k_decoder,  dim3(768),     dim3(256),  0, stream,
                       hin, dec_w1, dec_b1, dec_w2, dec_b2, out);
}